// Round 1
// 533.324 us; speedup vs baseline: 1.0746x; 1.0746x over previous
//
#include <hip/hip_runtime.h>
#include <hip/hip_fp16.h>

// GCN: h1 = relu(gcn(x,W1,b1)); h2 = relu(gcn(h1,W2,b2)); out = h2.reshape(B,896)@Wfc + bfc
// Factored BOTH layers past the aggregation (agg commutes with @W):
//   P  = dinv*x (fp16, 32 feat = 64B rows)           <- stage-1 gather table (44.8MB, L3-resident)
//   u1 = dinv*relu(dinv*(agg(P)@W1)+b1)  (fp16, 64 feat)
//   out= FC(relu((dinv*agg(u1))@W2+b2))
// CSR via deterministic counting sort (b=dst>>11), self-loop in-row, dummy zero row at N.
// Gather loops use the MFMA fragment layout: lane(m=lane&15, quad=lane>>4) owns 16B chunks
// of row m; clamped col -> unconditional dwordx4 gathers, pk_add fp16.
// Stage-1: 1 uint4/edge (row==A-fragment), 8 edges/iter in flight.
// Stage-2: 2 uint4/edge, 4 edges/iter in flight. Split even/odd accumulators.

typedef _Float16 half8 __attribute__((ext_vector_type(8)));
typedef float float4v __attribute__((ext_vector_type(4)));

#define CHUNK 8192
#define BSH 11
#define BNODES 2048

__global__ __launch_bounds__(256) void fallback_kernel(float* __restrict__ out, int n, float v)
{
  int i = blockIdx.x * 256 + threadIdx.x;
  if (i < n) out[i] = v;
}

// detect edges dtype: int64 values < 2^31 -> every odd int32 word is 0
__global__ __launch_bounds__(64) void probe_kernel(const int* __restrict__ edges, int* __restrict__ flag)
{
  if (threadIdx.x == 0) {
    int orv = edges[1] | edges[3] | edges[5] | edges[7] | edges[9] | edges[11] | edges[13] | edges[15];
    flag[0] = (orv == 0) ? 1 : 0;  // 1 => int64 layout (shift word index by 1)
  }
}

// zero the dummy rows (index N): P row = 64B, F2 row = 128B (ws is poisoned every call)
__global__ __launch_bounds__(64) void zero_dummy_kernel(
    __half* __restrict__ P, __half* __restrict__ F2, int N)
{
  int t = threadIdx.x;
  if (t < 8) ((uint2*)(P + (size_t)N * 32))[t] = make_uint2(0, 0);
  else if (t < 24) ((uint2*)(F2 + (size_t)N * 64))[t - 8] = make_uint2(0, 0);
}

// (1) per-chunk bucket histogram -> cnt[chunk][b]
__global__ __launch_bounds__(256) void hist2_kernel(
    const int* __restrict__ edges, int E, int N, const int* __restrict__ flag,
    int* __restrict__ cnt, int NBK)
{
  __shared__ int lh[512];
  int t = threadIdx.x;
  int blk = blockIdx.x;
  for (int b = t; b < NBK; b += 256) lh[b] = 0;
  __syncthreads();
  int sh = flag[0];
  int base = blk * CHUNK;
#pragma unroll
  for (int k = 0; k < CHUNK / 256; k++) {
    int e = base + k * 256 + t;
    if (e < E) {
      int d = edges[(E + e) << sh];
      if ((unsigned)d < (unsigned)N) atomicAdd(&lh[d >> BSH], 1);
    }
  }
  __syncthreads();
  for (int b = t; b < NBK; b += 256) cnt[(size_t)blk * NBK + b] = lh[b];
}

// (2) per-bucket exclusive prefix over chunks, in place; totals[b] = column sum
__global__ __launch_bounds__(64) void colscan_kernel(
    int* __restrict__ cnt, int NCH, int NBK, int* __restrict__ totals)
{
  int b = blockIdx.x;
  int lane = threadIdx.x;
  int carry = 0;
  int rounds = (NCH + 63) >> 6;
  for (int r = 0; r < rounds; r++) {
    int blk = r * 64 + lane;
    int v = (blk < NCH) ? cnt[(size_t)blk * NBK + b] : 0;
    int incl = v;
#pragma unroll
    for (int off = 1; off < 64; off <<= 1) {
      int x = __shfl_up(incl, off);
      if (lane >= off) incl += x;
    }
    int excl = incl - v + carry;
    if (blk < NCH) cnt[(size_t)blk * NBK + b] = excl;
    carry += __shfl(incl, 63);
  }
  if (lane == 0) totals[b] = carry;
}

// (3) exclusive scan of bucket totals -> bstart[NBK+1]; rowptr[N] = Ev + N
__global__ __launch_bounds__(512) void scan_totals_kernel(
    const int* __restrict__ totals, int NBK,
    int* __restrict__ bstart, int* __restrict__ rowptr, int N)
{
  __shared__ int sm[512];
  int t = threadIdx.x;
  int v = (t < NBK) ? totals[t] : 0;
  sm[t] = v;
  __syncthreads();
  for (int off = 1; off < 512; off <<= 1) {
    int x = 0;
    if (t >= off) x = sm[t - off];
    __syncthreads();
    if (t >= off) sm[t] += x;
    __syncthreads();
  }
  if (t < NBK) bstart[t] = sm[t] - v;
  if (t == 0) { bstart[NBK] = sm[511]; rowptr[N] = sm[511] + N; }
}

// (4) placement: contiguous runs per (chunk,bucket); packed = src | (dst&2047)<<20
__global__ __launch_bounds__(256) void pass3_kernel(
    const int* __restrict__ edges, int E, int N, const int* __restrict__ flag,
    const int* __restrict__ cnt, const int* __restrict__ bstart,
    int* __restrict__ pair, int NBK)
{
  __shared__ int lcur[512];
  int t = threadIdx.x;
  int blk = blockIdx.x;
  for (int b = t; b < NBK; b += 256)
    lcur[b] = bstart[b] + cnt[(size_t)blk * NBK + b];
  __syncthreads();
  int sh = flag[0];
  int base = blk * CHUNK;
#pragma unroll
  for (int k = 0; k < CHUNK / 256; k++) {
    int e = base + k * 256 + t;
    if (e < E) {
      int s = edges[e << sh];
      int d = edges[(E + e) << sh];
      if ((unsigned)s < (unsigned)N && (unsigned)d < (unsigned)N) {
        int pos = atomicAdd(&lcur[d >> BSH], 1);
        pair[pos] = s | ((d & (BNODES - 1)) << 20);
      }
    }
  }
}

// (5) per-bucket CSR build with self entry first in each row.
__global__ __launch_bounds__(256) void build_kernel(
    const int* __restrict__ pair, const int* __restrict__ bstart,
    int* __restrict__ rowptr, float* __restrict__ dinv, int* __restrict__ col, int N)
{
  __shared__ int hist[BNODES];
  __shared__ int cur[BNODES];
  __shared__ int sc[256];
  int b = blockIdx.x;
  int t = threadIdx.x;
  int pbeg = bstart[b], pend = bstart[b + 1];
  int colbase = pbeg + (b << BSH);
#pragma unroll
  for (int i = 0; i < BNODES / 256; i++) {
    int idx = i * 256 + t;
    int row = (b << BSH) + idx;
    hist[idx] = (row < N) ? 1 : 0;  // self entry
  }
  __syncthreads();
  for (int p = pbeg + t; p < pend; p += 256)
    atomicAdd(&hist[(pair[p] >> 20) & (BNODES - 1)], 1);
  __syncthreads();
  int hv[8];
  int tsum = 0;
#pragma unroll
  for (int i = 0; i < 8; i++) { hv[i] = hist[t * 8 + i]; tsum += hv[i]; }
  sc[t] = tsum;
  __syncthreads();
  for (int off = 1; off < 256; off <<= 1) {
    int x = 0;
    if (t >= off) x = sc[t - off];
    __syncthreads();
    if (t >= off) sc[t] += x;
    __syncthreads();
  }
  int run = sc[t] - tsum;
#pragma unroll
  for (int i = 0; i < 8; i++) {
    int idx = t * 8 + i;
    int rp = colbase + run;
    int row = (b << BSH) + idx;
    if (row < N) {
      rowptr[row] = rp;
      dinv[row] = rsqrtf((float)hv[i]);  // hv = deg + 1 (self included)
      col[rp] = row;                      // self entry at slot 0
      cur[idx] = rp + 1;
    } else {
      cur[idx] = rp;
    }
    run += hv[i];
  }
  __syncthreads();
  for (int p = pbeg + t; p < pend; p += 256) {
    int v = pair[p];
    int pos = atomicAdd(&cur[(v >> 20) & (BNODES - 1)], 1);
    col[pos] = v & 0xFFFFF;
  }
}

// P = dinv * x, fp16, 32 features = 64B rows. 4 threads/node, 32B each (coalesced).
__global__ __launch_bounds__(256) void scale_x_kernel(
    const float* __restrict__ X, const float* __restrict__ dinv,
    __half* __restrict__ P, int N)
{
  int idx = blockIdx.x * 256 + threadIdx.x;
  int total = N * 4;
  int stride = gridDim.x * 256;
  for (int i = idx; i < total; i += stride) {
    int node = i >> 2, part = i & 3;
    const float4* xp = (const float4*)(X + (size_t)node * 32 + part * 8);
    float dv = dinv[node];
    float4 v0 = xp[0], v1 = xp[1];
    half8 h;
    h[0] = (_Float16)(dv * v0.x); h[1] = (_Float16)(dv * v0.y);
    h[2] = (_Float16)(dv * v0.z); h[3] = (_Float16)(dv * v0.w);
    h[4] = (_Float16)(dv * v1.x); h[5] = (_Float16)(dv * v1.y);
    h[6] = (_Float16)(dv * v1.z); h[7] = (_Float16)(dv * v1.w);
    *(half8*)(P + (size_t)node * 32 + part * 8) = h;
  }
}

__device__ inline void hacc(uint4 v, __half2* a)
{
  a[0] = __hadd2(a[0], *reinterpret_cast<__half2*>(&v.x));
  a[1] = __hadd2(a[1], *reinterpret_cast<__half2*>(&v.y));
  a[2] = __hadd2(a[2], *reinterpret_cast<__half2*>(&v.z));
  a[3] = __hadd2(a[3], *reinterpret_cast<__half2*>(&v.w));
}

// FUSED agg1 + W1 matmul + bias + relu + dinv scale.
// Gather table P: 64B rows, one uint4 per edge per lane; the per-lane half8
// accumulator IS the 16x16x32 A-fragment (row=n16, k=quad*8+i). 8 edges/iter
// in flight, even/odd split accumulators. Epilogue: u1 = dinv*relu(dinv*(aggP@W1)+b1).
__global__ __launch_bounds__(256) void agg1_mfma_kernel(
    const __half* __restrict__ P, const int* __restrict__ rowptr,
    const int* __restrict__ col, const float* __restrict__ dinv,
    const float* __restrict__ W1, const float* __restrict__ b1,
    __half* __restrict__ U, int ntiles, int ndummy)
{
  int lane = threadIdx.x & 63;
  int n16 = lane & 15;
  int quad = lane >> 4;

  half8 bf[4];
#pragma unroll
  for (int jb = 0; jb < 4; jb++)
#pragma unroll
    for (int i = 0; i < 8; i++)
      bf[jb][i] = (_Float16)W1[(quad * 8 + i) * 64 + jb * 16 + n16];
  float b1j[4];
#pragma unroll
  for (int jb = 0; jb < 4; jb++) b1j[jb] = b1[jb * 16 + n16];

  const uint4* P4 = (const uint4*)P;
  _Float16* Uh = (_Float16*)U;
  int wave = (blockIdx.x * 256 + threadIdx.x) >> 6;
  int nw = (gridDim.x * 256) >> 6;
  for (int tile = wave; tile < ntiles; tile += nw) {
    int ut = __builtin_amdgcn_readfirstlane(tile);
    int base = ut * 16;
    int node = base + n16;  // N divisible by 16
    int rbeg = rowptr[node];
    int rlen = rowptr[node + 1] - rbeg;

    __half2 z2 = __float2half2_rn(0.f);
    __half2 aA[4] = {z2, z2, z2, z2};
    __half2 aB[4] = {z2, z2, z2, z2};

    for (int j = 0; __any(j < rlen); j += 8) {
      int c[8];
#pragma unroll
      for (int q = 0; q < 8; q++) {
        int cc = col[rbeg + j + q];  // slack-padded overread ok
        c[q] = (j + q < rlen) ? cc : ndummy;
      }
      uint4 v[8];
#pragma unroll
      for (int q = 0; q < 8; q++) v[q] = P4[((size_t)c[q] << 2) + quad];
#pragma unroll
      for (int q = 0; q < 8; q += 2) { hacc(v[q], aA); hacc(v[q + 1], aB); }
    }
#pragma unroll
    for (int k = 0; k < 4; k++) aA[k] = __hadd2(aA[k], aB[k]);

    half8 a = *reinterpret_cast<half8*>(aA);
    float4v co[4];
#pragma unroll
    for (int jb = 0; jb < 4; jb++) {
      float4v z = {0.f, 0.f, 0.f, 0.f};
      co[jb] = __builtin_amdgcn_mfma_f32_16x16x32_f16(a, bf[jb], z, 0, 0, 0);
    }
#pragma unroll
    for (int r = 0; r < 4; r++) {
      int node2 = base + quad * 4 + r;
      float dv = dinv[node2];
#pragma unroll
      for (int jb = 0; jb < 4; jb++) {
        float h = dv * co[jb][r] + b1j[jb];
        h = h > 0.f ? h : 0.f;
        Uh[(size_t)node2 * 64 + jb * 16 + n16] = (_Float16)(dv * h);
      }
    }
  }
}

__global__ __launch_bounds__(256) void out_init_kernel(
    float* __restrict__ out, const float* __restrict__ bfc, int n)
{
  int i = blockIdx.x * 256 + threadIdx.x;
  if (i < n) out[i] = bfc[0];
}

// FUSED agg2 + layer2-matmul + relu + FC. 4 edges/iter (8 dwordx4 in flight),
// even/odd split accumulators.
__global__ __launch_bounds__(256) void mfma_final_fused_kernel(
    const __half* __restrict__ U, const int* __restrict__ rowptr,
    const int* __restrict__ col, const float* __restrict__ dinv,
    const float* __restrict__ W2, const float* __restrict__ b2,
    const float* __restrict__ Wfc, float* __restrict__ out,
    int ntiles, int ndummy)
{
  int lane = threadIdx.x & 63;
  int n16 = lane & 15;
  int quad = lane >> 4;

  half8 bf[4][2];
#pragma unroll
  for (int jb = 0; jb < 4; jb++)
#pragma unroll
    for (int kf = 0; kf < 2; kf++)
#pragma unroll
      for (int i = 0; i < 8; i++)
        bf[jb][kf][i] = (_Float16)W2[(kf * 32 + quad * 8 + i) * 64 + jb * 16 + n16];
  float b2j[4];
#pragma unroll
  for (int jb = 0; jb < 4; jb++) b2j[jb] = b2[jb * 16 + n16];

  const uint4* U4 = (const uint4*)U;
  int wave = (blockIdx.x * 256 + threadIdx.x) >> 6;
  int nw = (gridDim.x * 256) >> 6;
  for (int tile = wave; tile < ntiles; tile += nw) {
    int ut = __builtin_amdgcn_readfirstlane(tile);
    int base = ut * 16;
    int node = base + n16;
    int rbeg = rowptr[node];
    int rlen = rowptr[node + 1] - rbeg;

    __half2 z2 = __float2half2_rn(0.f);
    __half2 aE0[4] = {z2, z2, z2, z2};
    __half2 aE1[4] = {z2, z2, z2, z2};
    __half2 aO0[4] = {z2, z2, z2, z2};
    __half2 aO1[4] = {z2, z2, z2, z2};

    for (int j = 0; __any(j < rlen); j += 4) {
      int c0 = col[rbeg + j];
      int c1 = col[rbeg + j + 1];  // slack-padded overread ok
      int c2 = col[rbeg + j + 2];
      int c3 = col[rbeg + j + 3];
      c0 = (j < rlen) ? c0 : ndummy;
      c1 = (j + 1 < rlen) ? c1 : ndummy;
      c2 = (j + 2 < rlen) ? c2 : ndummy;
      c3 = (j + 3 < rlen) ? c3 : ndummy;
      uint4 v00 = U4[((size_t)c0 << 3) + quad];
      uint4 v01 = U4[((size_t)c0 << 3) + 4 + quad];
      uint4 v10 = U4[((size_t)c1 << 3) + quad];
      uint4 v11 = U4[((size_t)c1 << 3) + 4 + quad];
      uint4 v20 = U4[((size_t)c2 << 3) + quad];
      uint4 v21 = U4[((size_t)c2 << 3) + 4 + quad];
      uint4 v30 = U4[((size_t)c3 << 3) + quad];
      uint4 v31 = U4[((size_t)c3 << 3) + 4 + quad];
      hacc(v00, aE0); hacc(v01, aE1);
      hacc(v10, aO0); hacc(v11, aO1);
      hacc(v20, aE0); hacc(v21, aE1);
      hacc(v30, aO0); hacc(v31, aO1);
    }
#pragma unroll
    for (int k = 0; k < 4; k++) {
      aE0[k] = __hadd2(aE0[k], aO0[k]);
      aE1[k] = __hadd2(aE1[k], aO1[k]);
    }
    // scale by dinv[node] -> a2 in A-fragment layout
    __half2 dv = __half2half2(__float2half_rn(dinv[node]));
#pragma unroll
    for (int j = 0; j < 4; j++) {
      aE0[j] = __hmul2(aE0[j], dv);
      aE1[j] = __hmul2(aE1[j], dv);
    }
    half8 a0 = *reinterpret_cast<half8*>(aE0);
    half8 a1 = *reinterpret_cast<half8*>(aE1);

    int g_r[4], t_r[4];
#pragma unroll
    for (int r = 0; r < 4; r++) {
      int nd = base + quad * 4 + r;
      g_r[r] = nd / 14;
      t_r[r] = nd - g_r[r] * 14;
    }
    float pr[4] = {0.f, 0.f, 0.f, 0.f};
#pragma unroll
    for (int jb = 0; jb < 4; jb++) {
      float4v acc = {0.f, 0.f, 0.f, 0.f};
      acc = __builtin_amdgcn_mfma_f32_16x16x32_f16(a0, bf[jb][0], acc, 0, 0, 0);
      acc = __builtin_amdgcn_mfma_f32_16x16x32_f16(a1, bf[jb][1], acc, 0, 0, 0);
      int j = jb * 16 + n16;
#pragma unroll
      for (int r = 0; r < 4; r++) {
        float h = acc[r] + b2j[jb];
        h = h > 0.f ? h : 0.f;
        pr[r] += h * Wfc[t_r[r] * 64 + j];
      }
    }
#pragma unroll
    for (int r = 0; r < 4; r++) {
#pragma unroll
      for (int off = 1; off < 16; off <<= 1) pr[r] += __shfl_xor(pr[r], off);
    }
    if (n16 == 0) {
#pragma unroll
      for (int r = 0; r < 4; r++) atomicAdd(&out[g_r[r]], pr[r]);
    }
  }
}

extern "C" void kernel_launch(void* const* d_in, const int* in_sizes, int n_in,
                              void* d_out, int out_size, void* d_ws, size_t ws_size,
                              hipStream_t stream)
{
  const float* x = (const float*)d_in[0];
  const int* edges = (const int*)d_in[1];
  const float* W1 = (const float*)d_in[2];
  const float* b1 = (const float*)d_in[3];
  const float* W2 = (const float*)d_in[4];
  const float* b2 = (const float*)d_in[5];
  const float* Wfc = (const float*)d_in[6];
  const float* bfc = (const float*)d_in[7];
  float* out = (float*)d_out;
  (void)n_in;

  const int N = in_sizes[0] / 32;   // 700000
  const int E = in_sizes[1] / 2;    // 4000000
  const int B = out_size;           // 50000
  const int NBK = (N + BNODES - 1) >> BSH;  // 342 buckets (dst>>11)
  const int NCH = (E + CHUNK - 1) / CHUNK;  // 489 chunks

  char* ws = (char*)d_ws;
  size_t off = 0;
  auto alloc = [&](size_t bytes) -> void* {
    void* p = ws + off;
    off += (bytes + 255) & ~(size_t)255;
    return p;
  };
  int* flag = (int*)alloc(256);
  int* cnt = (int*)alloc((size_t)NCH * NBK * 4);
  int* totals = (int*)alloc((size_t)NBK * 4);
  int* bstart = (int*)alloc(((size_t)NBK + 1) * 4);
  int* col = (int*)alloc(((size_t)E + N + 256) * 4);  // self entries + overread slack
  int* rowptr = (int*)alloc(((size_t)N + 1) * 4);
  float* dinv = (float*)alloc((size_t)N * 4);
  __half* P = (__half*)alloc(((size_t)N + 16) * 32 * 2);   // dinv*x fp16; head aliased as pairbuf
  __half* F2 = (__half*)alloc(((size_t)N + 16) * 64 * 2);  // u1
  int* pair = (int*)P;  // pairbuf (E*4 = 16MB) dead before scale_x writes P (44.8MB)

  if (off > ws_size) {
    float v = -(float)(double)(ws_size >> 20);
    fallback_kernel<<<(B + 255) / 256, 256, 0, stream>>>(out, B, v);
    return;
  }

  probe_kernel<<<1, 64, 0, stream>>>(edges, flag);
  zero_dummy_kernel<<<1, 64, 0, stream>>>(P, F2, N);
  hist2_kernel<<<NCH, 256, 0, stream>>>(edges, E, N, flag, cnt, NBK);
  colscan_kernel<<<NBK, 64, 0, stream>>>(cnt, NCH, NBK, totals);
  scan_totals_kernel<<<1, 512, 0, stream>>>(totals, NBK, bstart, rowptr, N);
  pass3_kernel<<<NCH, 256, 0, stream>>>(edges, E, N, flag, cnt, bstart, pair, NBK);
  build_kernel<<<NBK, 256, 0, stream>>>(pair, bstart, rowptr, dinv, col, N);

  int ntiles = (N + 15) / 16;  // 43750 (N divisible by 16)
  scale_x_kernel<<<2048, 256, 0, stream>>>(x, dinv, P, N);
  agg1_mfma_kernel<<<4096, 256, 0, stream>>>(P, rowptr, col, dinv, W1, b1, F2, ntiles, N);
  out_init_kernel<<<(B + 255) / 256, 256, 0, stream>>>(out, bfc, B);
  mfma_final_fused_kernel<<<4096, 256, 0, stream>>>(F2, rowptr, col, dinv, W2, b2, Wfc,
                                                    out, ntiles, N);
}